// Round 10
// baseline (188.555 us; speedup 1.0000x reference)
//
#include <hip/hip_runtime.h>
#include <cstddef>
#include <cstdint>

#define NT_ 4096
#define NV_ 128
#define NH_ 256
#define NC_ 10
#define KT_ 384            // NV_ + NH_
#define NGRP 16            // sample groups
#define SB   8             // samples per group
#define GWG  16            // workgroups per group
#define TPW  256
#define VST  12            // v_lds row stride (floats), 16B-aligned, bank-clean
#define Z9   9             // zp row pad (float4s)
#define FULLMASK 255

// dynamic LDS partition (float offsets)
#define SM_W    0                        // 24576: weight slice (96KB)
#define SM_V    24576                    // 4608:  v = [x;h] rows [384][VST]
#define SM_ZP   (SM_V + KT_*VST)         // 29184: zp 64*Z9 float4 = 2304 (also leader head scratch)
#define SM_C    (SM_ZP + 2304)           // 31488: c[16][Z9]
#define SM_BL   (SM_C + 144)             // 31632: bias slice [64]
#define SM_WC   (SM_BL + 64)             // 31696: full Wc [257] (every WG)
#define SM_WO   (SM_WC + 260)            // 31956: leader Wo [256*10]
#define SM_HD   (SM_WO + 2560)           // 34516: bo[10], bc0
#define SM_RED  (SM_HD + 12)             // 34528: head wave partials [4][8]
#define SM_TOT  (SM_RED + 32)            // 34560 floats
#define SMEM_BYTES (SM_TOT * 4)          // 138240 B

// d_ws layout: cnt[16 groups][4 lines @ 256B] = 16KB ; hbuf[2][16][256][8] floats
#define WS_HBUF  16384

#define ALD(p)    __hip_atomic_load((p), __ATOMIC_RELAXED, __HIP_MEMORY_SCOPE_AGENT)
#define AST(p,v)  __hip_atomic_store((p), (v), __ATOMIC_RELAXED, __HIP_MEMORY_SCOPE_AGENT)

#define FMA8(S) \
  acc[S].x = fmaf(w4.x, vs, acc[S].x); \
  acc[S].y = fmaf(w4.y, vs, acc[S].y); \
  acc[S].z = fmaf(w4.z, vs, acc[S].z); \
  acc[S].w = fmaf(w4.w, vs, acc[S].w);

extern "C" __global__ __launch_bounds__(TPW, 1)
void earliest_coop(const float* __restrict__ X, const float* __restrict__ U,
                   const float* __restrict__ Wk, const float* __restrict__ Wr,
                   const float* __restrict__ bl, const float* __restrict__ Wo,
                   const float* __restrict__ bo, const float* __restrict__ Wc,
                   const float* __restrict__ bc, float* __restrict__ out,
                   int* __restrict__ cnt, float* __restrict__ hbuf)
{
  extern __shared__ float smem[];
  float* w_lds = smem + SM_W;
  float* v_lds = smem + SM_V;
  float* zp    = smem + SM_ZP;
  float* c_lds = smem + SM_C;
  float* bl_s  = smem + SM_BL;
  float* wc_s  = smem + SM_WC;
  float* wo_s  = smem + SM_WO;
  float* hd_s  = smem + SM_HD;
  float* red   = smem + SM_RED;
  __shared__ int halted_lds;   // replicated (deterministic, identical in all WGs)
  __shared__ int wflags;       // samples needing an out-write this iter

  const int tid  = threadIdx.x;
  const int w    = blockIdx.x & 15;   // WG within group
  const int g    = blockIdx.x >> 4;   // group
  const int colq = tid & 15;          // col-quad within WG (16 x float4 = 64 cols)
  const int ks   = tid >> 4;          // K-split 0..15
  const bool leader = (w == 0);

  // ---- one-time: stage weight slice into LDS (swizzled) ----
  for (int m = 0; m < 24; ++m) {
    int idx4 = m * 256 + tid;
    int k = idx4 >> 4, cq = idx4 & 15;
    int rr = cq >> 2, qq = cq & 3;
    int col4 = rr * 64 + w * 4 + qq;            // float4 column index in [0,256)
    float4 wv;
    if (k < NV_) wv = ((const float4*)Wk)[(size_t)k * 256 + col4];
    else         wv = ((const float4*)Wr)[(size_t)(k - NV_) * 256 + col4];
    ((float4*)w_lds)[k * 16 + (cq ^ (k & 7))] = wv;
  }
  if (tid < 64) {
    int rr = tid >> 4, e = tid & 15;
    bl_s[tid] = bl[rr * 256 + w * 16 + e];
  }
  wc_s[tid] = Wc[tid];
  if (tid == 0) wc_s[256] = Wc[256];
  if (tid < 128) c_lds[(tid >> 3) * Z9 + (tid & 7)] = 0.f;
  if (leader) {
    for (int m = tid; m < NH_ * NC_; m += TPW) wo_s[m] = Wo[m];
  }
  if (tid < 10)  hd_s[tid] = bo[tid];
  if (tid == 10) hd_s[10] = bc[0];
  if (tid == 0)  { halted_lds = 0; wflags = 0; }

  int* cntg = cnt + (g << 8);         // 4 lines at +0,+64,+128,+192 ints (256B apart)
  const int cswz  = colq ^ (ks & 7);
  const int wbase = ks * 16 + cswz;

  // X staging decomposition: one float4 per thread per iter
  const int xk4 = tid >> 3;        // 0..31 (float4 row index)
  const int xs  = tid & 7;         // sample
  const float4* X4 = (const float4*)X;
  float4 xr = X4[((size_t)(g * SB + xs) * NT_ + 0) * 32 + xk4];  // prefetch it=0

  // prologue: stage x(0) into v_lds (h region staged in-loop at it=0)
  __syncthreads();   // staging + shared-init visible; xr arrived
  {
    #pragma unroll
    for (int j = 0; j < 4; ++j)
      v_lds[(4 * xk4 + j) * VST + xs] = ((const float*)&xr)[j];
  }

  float uv_pf = 0.f;   // prefetched U(tau) for decision lanes

  for (int it = 0;; ++it) {
    // ---- A: stage h(it-1) into v_lds; reset wflags ----
    if (tid == 0) wflags = 0;
    if (it == 0) {
      #pragma unroll
      for (int i2 = 0; i2 < 8; ++i2) {
        int flat = i2 * 256 + tid;
        v_lds[(NV_ + (flat >> 3)) * VST + (flat & 7)] = 0.f;
      }
    } else {
      const float* hsrc = hbuf + ((size_t)(it & 1) * NGRP + g) * NH_ * SB;
      #pragma unroll
      for (int i2 = 0; i2 < 8; ++i2) {
        int flat = i2 * 256 + tid;
        v_lds[(NV_ + (flat >> 3)) * VST + (flat & 7)] = ALD(hsrc + flat);
      }
    }
    __syncthreads();   // B1: v_lds (x staged last window + h) + wflags reset visible

    // ---- C: z-phase + head partials + prefetches (one block, no barrier inside) ----
    if (it < NT_) {
      if (it + 1 < NT_)   // prefetch X(it+1) (hidden under compute)
        xr = X4[((size_t)(g * SB + xs) * NT_ + (it + 1)) * 32 + xk4];

      float4 acc[8];
      #pragma unroll
      for (int s = 0; s < 8; ++s) acc[s] = make_float4(0.f, 0.f, 0.f, 0.f);
      {
        const float4* wl4 = (const float4*)w_lds;
        #pragma unroll
        for (int i = 0; i < 24; ++i) {
          int k = i * 16 + ks;
          float4 w4 = wl4[i * 256 + wbase];
          const float* vk = v_lds + k * VST;
          float4 va = *(const float4*)(vk);
          float4 vb = *(const float4*)(vk + 4);
          { float vs = va.x; FMA8(0) } { float vs = va.y; FMA8(1) }
          { float vs = va.z; FMA8(2) } { float vs = va.w; FMA8(3) }
          { float vs = vb.x; FMA8(4) } { float vs = vb.y; FMA8(5) }
          { float vs = vb.z; FMA8(6) } { float vs = vb.w; FMA8(7) }
        }
      }
      #pragma unroll
      for (int off = 16; off <= 32; off <<= 1) {
        #pragma unroll
        for (int s = 0; s < 8; ++s) {
          acc[s].x += __shfl_xor(acc[s].x, off, 64);
          acc[s].y += __shfl_xor(acc[s].y, off, 64);
          acc[s].z += __shfl_xor(acc[s].z, off, 64);
          acc[s].w += __shfl_xor(acc[s].w, off, 64);
        }
      }
      if ((tid & 48) == 0) {   // ks&3 == 0 lanes
        int w4 = tid >> 6;
        float4* zp4 = (float4*)zp;
        #pragma unroll
        for (int s = 0; s < 8; ++s) zp4[(w4 * 16 + colq) * Z9 + s] = acc[s];
      }
    }
    if (it >= 1) {
      // head partials for tau = it-1 (reads v_lds h region; independent of z)
      const float* hv = v_lds + (NV_ + tid) * VST;
      const float wcv = wc_s[tid];
      float part[SB];
      #pragma unroll
      for (int s = 0; s < SB; ++s) part[s] = hv[s] * wcv;
      #pragma unroll
      for (int off = 1; off <= 32; off <<= 1) {
        #pragma unroll
        for (int s = 0; s < SB; ++s) part[s] += __shfl_xor(part[s], off, 64);
      }
      if ((tid & 63) == 0) {
        int w4 = tid >> 6;
        #pragma unroll
        for (int s = 0; s < SB; ++s) red[w4 * 8 + s] = part[s];
      }
      // prefetch U(tau) for decision lanes
      if (tid >= 128 && tid < 128 + SB)
        uv_pf = U[(size_t)(g * SB + (tid - 128)) * NT_ + (it - 1)];
    }
    __syncthreads();   // B5: zp + red visible

    // ---- E: gates (waves 0-1) || halt decision (wave 2 lanes 0-7) ----
    if (it < NT_ && tid < 128) {
      int e = tid >> 3, s = tid & 7;
      float zg4[4];
      #pragma unroll
      for (int r = 0; r < 4; ++r) {
        int cq = r * 4 + (e >> 2);
        int j  = e & 3;
        float sum = 0.f;
        #pragma unroll
        for (int w4 = 0; w4 < 4; ++w4)
          sum += zp[((w4 * 16 + cq) * Z9 + s) * 4 + j];
        zg4[r] = sum + bl_s[r * 16 + e];
      }
      float gi = 1.f / (1.f + expf(-zg4[0]));
      float gf = 1.f / (1.f + expf(-zg4[1]));
      float gg = tanhf(zg4[2]);
      float go = 1.f / (1.f + expf(-zg4[3]));
      float c = gf * c_lds[e * Z9 + s] + gi * gg;
      c_lds[e * Z9 + s] = c;
      float h = go * tanhf(c);
      size_t hidx = (((size_t)((it + 1) & 1) * NGRP + g) * NH_ + (w * 16 + e)) * SB + s;
      AST(hbuf + hidx, h);
    }
    if (it >= 1 && tid >= 128 && tid < 128 + SB) {
      const int s_ = tid - 128;
      if (!((halted_lds >> s_) & 1)) {
        const int tau = it - 1;
        const float psum = red[0 * 8 + s_] + red[1 * 8 + s_] + red[2 * 8 + s_] + red[3 * 8 + s_];
        const float pre   = psum + (float)tau * wc_s[256] + hd_s[10];
        const float p     = 1.f / (1.f + expf(-pre));
        const float probs = 0.9f * p + 0.005f;
        const bool  a     = (uv_pf < probs);
        if (a || tau == NT_ - 1) atomicOr(&wflags, 1 << s_);
        if (a) atomicOr(&halted_lds, 1 << s_);
      }
    }
    __syncthreads();   // B6: h stores drained (vmcnt0) + halted/wflags visible

    // ---- H: sync-overlap window ----
    if (tid == 0)       // arrival: 4-way split counter line (w&3), h already MALL-acked
      __hip_atomic_fetch_add(cntg + ((w & 3) << 6), 1, __ATOMIC_RELAXED, __HIP_MEMORY_SCOPE_AGENT);

    if (it + 1 < NT_) { // stage x(it+1) (independent of the group sync)
      #pragma unroll
      for (int j = 0; j < 4; ++j)
        v_lds[(4 * xk4 + j) * VST + xs] = ((const float*)&xr)[j];
    }

    if (it >= 1 && leader && wflags) {   // rare: logits + softmax + out write
      const int e5 = tid >> 3, s = tid & 7;
      float accv[NC_];
      #pragma unroll
      for (int cc = 0; cc < NC_; ++cc) accv[cc] = 0.f;
      #pragma unroll
      for (int i2 = 0; i2 < 8; ++i2) {
        const int e = i2 * 32 + e5;
        const float hvv = v_lds[(NV_ + e) * VST + s];
        #pragma unroll
        for (int cc = 0; cc < NC_; ++cc) accv[cc] += hvv * wo_s[e * NC_ + cc];
      }
      #pragma unroll
      for (int off = 8; off <= 32; off <<= 1) {
        #pragma unroll
        for (int cc = 0; cc < NC_; ++cc) accv[cc] += __shfl_xor(accv[cc], off, 64);
      }
      if ((tid & 56) == 0) {
        const int w4 = tid >> 6;
        #pragma unroll
        for (int cc = 0; cc < NC_; ++cc) zp[(w4 * 8 + s) * NC_ + cc] = accv[cc];
      }
      __syncthreads();   // leader-local
      if (tid < SB && ((wflags >> tid) & 1)) {
        const int s_ = tid;
        float l[NC_];
        float mx = -1e30f;
        #pragma unroll
        for (int cc = 0; cc < NC_; ++cc) {
          l[cc] = zp[(0 * 8 + s_) * NC_ + cc] + zp[(1 * 8 + s_) * NC_ + cc]
                + zp[(2 * 8 + s_) * NC_ + cc] + zp[(3 * 8 + s_) * NC_ + cc] + hd_s[cc];
          mx = fmaxf(mx, l[cc]);
        }
        float ssum = 0.f;
        #pragma unroll
        for (int cc = 0; cc < NC_; ++cc) { l[cc] = expf(l[cc] - mx); ssum += l[cc]; }
        const float inv = 1.f / ssum;
        float* op = out + (g * SB + s_) * NC_;
        #pragma unroll
        for (int cc = 0; cc < NC_; ++cc) op[cc] = l[cc] * inv;
      }
      __syncthreads();   // leader-local: zp scratch free before next z-phase
    }

    if (halted_lds == FULLMASK || it == NT_) break;   // identical decision in all WGs

    // ---- spin: tight 4-line poll with VALU burn (anti-DVFS, no s_sleep) ----
    if (tid == 0) {
      const int target = (it + 1) << 4;   // 16*(it+1) total arrivals
      float f0 = 1.0f;
      for (;;) {
        int s = ALD(cntg) + ALD(cntg + 64) + ALD(cntg + 128) + ALD(cntg + 192);
        if (s >= target) break;
        #pragma unroll
        for (int r = 0; r < 64; ++r) f0 = fmaf(f0, 1.0000001f, 1e-7f);
        asm volatile("" : "+v"(f0));    // keep burn chain live + ordered
      }
      asm volatile("" :: "v"(f0));
    }
    __syncthreads();   // B7
  }
}

extern "C" void kernel_launch(void* const* d_in, const int* in_sizes, int n_in,
                              void* d_out, int out_size, void* d_ws, size_t ws_size,
                              hipStream_t stream)
{
  const float* X  = (const float*)d_in[0];
  const float* U  = (const float*)d_in[1];
  const float* Wk = (const float*)d_in[2];
  const float* Wr = (const float*)d_in[3];
  const float* bL = (const float*)d_in[4];
  const float* Wo = (const float*)d_in[5];
  const float* bo = (const float*)d_in[6];
  const float* Wc = (const float*)d_in[7];
  const float* bc = (const float*)d_in[8];
  float* out = (float*)d_out;

  int*   cnt  = (int*)d_ws;
  float* hbuf = (float*)((char*)d_ws + WS_HBUF);

  hipMemsetAsync(d_ws, 0, WS_HBUF, stream);   // zero all counter lines each call

  hipFuncSetAttribute((const void*)earliest_coop,
                      hipFuncAttributeMaxDynamicSharedMemorySize, SMEM_BYTES);

  void* args[] = { (void*)&X, (void*)&U, (void*)&Wk, (void*)&Wr, (void*)&bL,
                   (void*)&Wo, (void*)&bo, (void*)&Wc, (void*)&bc, (void*)&out,
                   (void*)&cnt, (void*)&hbuf };
  hipError_t lerr = hipLaunchCooperativeKernel((const void*)earliest_coop,
                                               dim3(NGRP * GWG), dim3(TPW),
                                               args, SMEM_BYTES, stream);
  if (lerr != hipSuccess) {
    hipLaunchKernelGGL(earliest_coop, dim3(NGRP * GWG), dim3(TPW), SMEM_BYTES, stream,
                       X, U, Wk, Wr, bL, Wo, bo, Wc, bc, out, cnt, hbuf);
  }
}

// Round 11
// 181.389 us; speedup vs baseline: 1.0395x; 1.0395x over previous
//
#include <hip/hip_runtime.h>
#include <cstddef>
#include <cstdint>

#define NT_ 4096
#define NV_ 128
#define NH_ 256
#define NC_ 10
#define KT_ 384            // NV_ + NH_
#define NGRP 16            // sample groups
#define SB   8             // samples per group
#define GWG  16            // workgroups per group
#define TPW  256
#define VST  12            // v_lds row stride (floats), 16B-aligned, bank-clean
#define Z9   9             // zp row pad (float4s)
#define FULLMASK 255

// dynamic LDS partition (float offsets)
#define SM_W    0                        // 24576: weight slice (96KB)
#define SM_V    24576                    // 4608:  v = [x;h] rows [384][VST]
#define SM_ZP   (SM_V + KT_*VST)         // 29184: zp 64*Z9 float4 = 2304 (also leader head scratch)
#define SM_C    (SM_ZP + 2304)           // 31488: c[16][Z9]
#define SM_BL   (SM_C + 144)             // 31632: bias slice [64]
#define SM_WC   (SM_BL + 64)             // 31696: full Wc [257] (every WG)
#define SM_WO   (SM_WC + 260)            // 31956: leader Wo [256*10]
#define SM_HD   (SM_WO + 2560)           // 34516: bo[10], bc0
#define SM_RED  (SM_HD + 12)             // 34528: head wave partials [4][8]
#define SM_TOT  (SM_RED + 32)            // 34560 floats
#define SMEM_BYTES (SM_TOT * 4)          // 138240 B

// d_ws layout: cnt[16] @ stride 256B (4KB) ; hbuf[2][16][256][8] floats (128KB);
//              diag lines at +1MB (4MB, optional)
#define WS_HBUF  4096
#define WS_DIAG  (1u << 20)

#define ALD(p)    __hip_atomic_load((p), __ATOMIC_RELAXED, __HIP_MEMORY_SCOPE_AGENT)
#define AST(p,v)  __hip_atomic_store((p), (v), __ATOMIC_RELAXED, __HIP_MEMORY_SCOPE_AGENT)

#define FMA8(S) \
  acc[S].x = fmaf(w4.x, vs, acc[S].x); \
  acc[S].y = fmaf(w4.y, vs, acc[S].y); \
  acc[S].z = fmaf(w4.z, vs, acc[S].z); \
  acc[S].w = fmaf(w4.w, vs, acc[S].w);

#define ZSTEP(i)                                            \
  {                                                         \
    float4 w4 = wl4[(i) * 256 + wbase];                     \
    const float* vk = v_lds + ((i) * 16 + ks) * VST;        \
    float4 va = *(const float4*)(vk);                       \
    float4 vb = *(const float4*)(vk + 4);                   \
    { float vs = va.x; FMA8(0) } { float vs = va.y; FMA8(1) } \
    { float vs = va.z; FMA8(2) } { float vs = va.w; FMA8(3) } \
    { float vs = vb.x; FMA8(4) } { float vs = vb.y; FMA8(5) } \
    { float vs = vb.z; FMA8(6) } { float vs = vb.w; FMA8(7) } \
  }

extern "C" __global__ __launch_bounds__(TPW, 1)
void earliest_coop(const float* __restrict__ X, const float* __restrict__ U,
                   const float* __restrict__ Wk, const float* __restrict__ Wr,
                   const float* __restrict__ bl, const float* __restrict__ Wo,
                   const float* __restrict__ bo, const float* __restrict__ Wc,
                   const float* __restrict__ bc, float* __restrict__ out,
                   int* __restrict__ cnt, float* __restrict__ hbuf,
                   char* __restrict__ diag)
{
  extern __shared__ float smem[];
  float* w_lds = smem + SM_W;
  float* v_lds = smem + SM_V;
  float* zp    = smem + SM_ZP;
  float* c_lds = smem + SM_C;
  float* bl_s  = smem + SM_BL;
  float* wc_s  = smem + SM_WC;
  float* wo_s  = smem + SM_WO;
  float* hd_s  = smem + SM_HD;
  float* red   = smem + SM_RED;
  __shared__ int halted_lds;   // replicated (deterministic, identical in all WGs)
  __shared__ int wflags;       // samples needing an out-write this iter

  const int tid  = threadIdx.x;
  const int w    = blockIdx.x & 15;   // WG within group
  const int g    = blockIdx.x >> 4;   // group
  const int colq = tid & 15;          // col-quad within WG (16 x float4 = 64 cols)
  const int ks   = tid >> 4;          // K-split 0..15
  const bool leader = (w == 0);

  // ---- one-time: stage weight slice into LDS (swizzled) ----
  for (int m = 0; m < 24; ++m) {
    int idx4 = m * 256 + tid;
    int k = idx4 >> 4, cq = idx4 & 15;
    int rr = cq >> 2, qq = cq & 3;
    int col4 = rr * 64 + w * 4 + qq;            // float4 column index in [0,256)
    float4 wv;
    if (k < NV_) wv = ((const float4*)Wk)[(size_t)k * 256 + col4];
    else         wv = ((const float4*)Wr)[(size_t)(k - NV_) * 256 + col4];
    ((float4*)w_lds)[k * 16 + (cq ^ (k & 7))] = wv;
  }
  if (tid < 64) {
    int rr = tid >> 4, e = tid & 15;
    bl_s[tid] = bl[rr * 256 + w * 16 + e];
  }
  wc_s[tid] = Wc[tid];
  if (tid == 0) wc_s[256] = Wc[256];
  if (tid < 128) c_lds[(tid >> 3) * Z9 + (tid & 7)] = 0.f;
  if (leader) {
    for (int m = tid; m < NH_ * NC_; m += TPW) wo_s[m] = Wo[m];
  }
  if (tid < 10)  hd_s[tid] = bo[tid];
  if (tid == 10) hd_s[10] = bc[0];
  if (tid == 0)  { halted_lds = 0; wflags = 0; }

  int* cntg = cnt + (g << 6);
  const int cswz  = colq ^ (ks & 7);
  const int wbase = ks * 16 + cswz;
  const float4* wl4 = (const float4*)w_lds;

  // X staging decomposition: one float4 per thread per iter
  const int xk4 = tid >> 3;        // 0..31 (float4 row index)
  const int xs  = tid & 7;         // sample
  const float4* X4 = (const float4*)X;
  float4 xr = X4[((size_t)(g * SB + xs) * NT_ + 0) * 32 + xk4];  // prefetch it=0

  __syncthreads();   // staging + shared-init visible; xr arrived
  // prologue: stage x(0), then Wk-pass for it=0
  {
    #pragma unroll
    for (int j = 0; j < 4; ++j)
      v_lds[(4 * xk4 + j) * VST + xs] = ((const float*)&xr)[j];
  }
  __syncthreads();   // x(0) visible for prologue Wk-pass

  float4 acc[8];     // persistent z accumulator (Wk part carried across sync)
  #pragma unroll
  for (int s = 0; s < 8; ++s) acc[s] = make_float4(0.f, 0.f, 0.f, 0.f);
  #pragma unroll
  for (int i = 0; i < 8; ++i) ZSTEP(i)   // x(0) @ Wk

  float uv_pf = 0.f;   // prefetched U(tau) for decision lanes

  for (int it = 0;; ++it) {
    // ---- A: stage h(it-1) into v_lds; reset wflags ----
    if (tid == 0) wflags = 0;
    if (it == 0) {
      #pragma unroll
      for (int i2 = 0; i2 < 8; ++i2) {
        int flat = i2 * 256 + tid;
        v_lds[(NV_ + (flat >> 3)) * VST + (flat & 7)] = 0.f;
      }
    } else {
      const float* hsrc = hbuf + ((size_t)(it & 1) * NGRP + g) * NH_ * SB;
      #pragma unroll
      for (int i2 = 0; i2 < 8; ++i2) {
        int flat = i2 * 256 + tid;
        v_lds[(NV_ + (flat >> 3)) * VST + (flat & 7)] = ALD(hsrc + flat);
      }
    }
    __syncthreads();   // B1: v_lds h region + wflags reset visible

    // ---- C: z h-part (i=8..23) + head partials + prefetches ----
    if (it < NT_) {
      if (it + 1 < NT_)   // prefetch X(it+1) (hidden under compute)
        xr = X4[((size_t)(g * SB + xs) * NT_ + (it + 1)) * 32 + xk4];
      #pragma unroll
      for (int i = 8; i < 24; ++i) ZSTEP(i)   // h(it-1) @ Wr (accumulates on Wk part)
      #pragma unroll
      for (int off = 16; off <= 32; off <<= 1) {
        #pragma unroll
        for (int s = 0; s < 8; ++s) {
          acc[s].x += __shfl_xor(acc[s].x, off, 64);
          acc[s].y += __shfl_xor(acc[s].y, off, 64);
          acc[s].z += __shfl_xor(acc[s].z, off, 64);
          acc[s].w += __shfl_xor(acc[s].w, off, 64);
        }
      }
      if ((tid & 48) == 0) {   // ks&3 == 0 lanes
        int w4 = tid >> 6;
        float4* zp4 = (float4*)zp;
        #pragma unroll
        for (int s = 0; s < 8; ++s) zp4[(w4 * 16 + colq) * Z9 + s] = acc[s];
      }
    }
    if (it >= 1) {
      // head partials for tau = it-1 (reads v_lds h region; independent of z)
      const float* hv = v_lds + (NV_ + tid) * VST;
      const float wcv = wc_s[tid];
      float part[SB];
      #pragma unroll
      for (int s = 0; s < SB; ++s) part[s] = hv[s] * wcv;
      #pragma unroll
      for (int off = 1; off <= 32; off <<= 1) {
        #pragma unroll
        for (int s = 0; s < SB; ++s) part[s] += __shfl_xor(part[s], off, 64);
      }
      if ((tid & 63) == 0) {
        int w4 = tid >> 6;
        #pragma unroll
        for (int s = 0; s < SB; ++s) red[w4 * 8 + s] = part[s];
      }
      if (tid >= 128 && tid < 128 + SB)
        uv_pf = U[(size_t)(g * SB + (tid - 128)) * NT_ + (it - 1)];
    }
    __syncthreads();   // B5: zp + red visible

    // ---- E: gates (waves 0-1) || halt decision (wave 2 lanes 0-7) ----
    if (it < NT_ && tid < 128) {
      int e = tid >> 3, s = tid & 7;
      float zg4[4];
      #pragma unroll
      for (int r = 0; r < 4; ++r) {
        int cq = r * 4 + (e >> 2);
        int j  = e & 3;
        float sum = 0.f;
        #pragma unroll
        for (int w4 = 0; w4 < 4; ++w4)
          sum += zp[((w4 * 16 + cq) * Z9 + s) * 4 + j];
        zg4[r] = sum + bl_s[r * 16 + e];
      }
      float gi = 1.f / (1.f + expf(-zg4[0]));
      float gf = 1.f / (1.f + expf(-zg4[1]));
      float gg = tanhf(zg4[2]);
      float go = 1.f / (1.f + expf(-zg4[3]));
      float c = gf * c_lds[e * Z9 + s] + gi * gg;
      c_lds[e * Z9 + s] = c;
      float h = go * tanhf(c);
      size_t hidx = (((size_t)((it + 1) & 1) * NGRP + g) * NH_ + (w * 16 + e)) * SB + s;
      AST(hbuf + hidx, h);
    }
    if (it >= 1 && tid >= 128 && tid < 128 + SB) {
      const int s_ = tid - 128;
      if (!((halted_lds >> s_) & 1)) {
        const int tau = it - 1;
        const float psum = red[0 * 8 + s_] + red[1 * 8 + s_] + red[2 * 8 + s_] + red[3 * 8 + s_];
        const float pre   = psum + (float)tau * wc_s[256] + hd_s[10];
        const float p     = 1.f / (1.f + expf(-pre));
        const float probs = 0.9f * p + 0.005f;
        const bool  a     = (uv_pf < probs);
        if (a || tau == NT_ - 1) atomicOr(&wflags, 1 << s_);
        if (a) atomicOr(&halted_lds, 1 << s_);
      }
    }
    __syncthreads();   // B6: h stores drained (vmcnt0) + halted/wflags visible

    // ---- H: sync-overlap window ----
    if (tid == 0) {   // arrival first (h already MALL-acked by B6)
      __hip_atomic_fetch_add(cntg, 1, __ATOMIC_RELAXED, __HIP_MEMORY_SCOPE_AGENT);
      if (diag)       // iteration meter: one 64B line per WG per iter (counted in WRITE_SIZE)
        __builtin_nontemporal_store(1u,
            (uint32_t*)(diag + (((size_t)blockIdx.x << 8) + (it & 255)) * 64));
    }

    if (it + 1 < NT_) { // stage x(it+1) (independent of the group sync)
      #pragma unroll
      for (int j = 0; j < 4; ++j)
        v_lds[(4 * xk4 + j) * VST + xs] = ((const float*)&xr)[j];
    }

    if (it >= 1 && leader && wflags) {   // rare: logits + softmax + out write
      const int e5 = tid >> 3, s = tid & 7;
      float accv[NC_];
      #pragma unroll
      for (int cc = 0; cc < NC_; ++cc) accv[cc] = 0.f;
      #pragma unroll
      for (int i2 = 0; i2 < 8; ++i2) {
        const int e = i2 * 32 + e5;
        const float hvv = v_lds[(NV_ + e) * VST + s];
        #pragma unroll
        for (int cc = 0; cc < NC_; ++cc) accv[cc] += hvv * wo_s[e * NC_ + cc];
      }
      #pragma unroll
      for (int off = 8; off <= 32; off <<= 1) {
        #pragma unroll
        for (int cc = 0; cc < NC_; ++cc) accv[cc] += __shfl_xor(accv[cc], off, 64);
      }
      if ((tid & 56) == 0) {
        const int w4 = tid >> 6;
        #pragma unroll
        for (int cc = 0; cc < NC_; ++cc) zp[(w4 * 8 + s) * NC_ + cc] = accv[cc];
      }
      __syncthreads();   // leader-local
      if (tid < SB && ((wflags >> tid) & 1)) {
        const int s_ = tid;
        float l[NC_];
        float mx = -1e30f;
        #pragma unroll
        for (int cc = 0; cc < NC_; ++cc) {
          l[cc] = zp[(0 * 8 + s_) * NC_ + cc] + zp[(1 * 8 + s_) * NC_ + cc]
                + zp[(2 * 8 + s_) * NC_ + cc] + zp[(3 * 8 + s_) * NC_ + cc] + hd_s[cc];
          mx = fmaxf(mx, l[cc]);
        }
        float ssum = 0.f;
        #pragma unroll
        for (int cc = 0; cc < NC_; ++cc) { l[cc] = expf(l[cc] - mx); ssum += l[cc]; }
        const float inv = 1.f / ssum;
        float* op = out + (g * SB + s_) * NC_;
        #pragma unroll
        for (int cc = 0; cc < NC_; ++cc) op[cc] = l[cc] * inv;
      }
      __syncthreads();   // leader-local: zp scratch free before next z-phase
    }

    if (halted_lds == FULLMASK || it == NT_) break;   // identical decision in all WGs

    __syncthreads();   // B6b: x(it+1) visible for the Wk-pass

    // ---- W: Wk-pass for z(it+1) — fills the sync window with local work ----
    #pragma unroll
    for (int s = 0; s < 8; ++s) acc[s] = make_float4(0.f, 0.f, 0.f, 0.f);
    if (it + 1 < NT_) {
      #pragma unroll
      for (int i = 0; i < 8; ++i) ZSTEP(i)   // x(it+1) @ Wk
    }

    // ---- spin (mostly pre-satisfied after the Wk-pass) ----
    if (tid == 0) {
      const int target = GWG * (it + 1);
      while (ALD(cntg) < target) __builtin_amdgcn_s_sleep(1);
    }
    __syncthreads();   // B7
  }
}

extern "C" void kernel_launch(void* const* d_in, const int* in_sizes, int n_in,
                              void* d_out, int out_size, void* d_ws, size_t ws_size,
                              hipStream_t stream)
{
  const float* X  = (const float*)d_in[0];
  const float* U  = (const float*)d_in[1];
  const float* Wk = (const float*)d_in[2];
  const float* Wr = (const float*)d_in[3];
  const float* bL = (const float*)d_in[4];
  const float* Wo = (const float*)d_in[5];
  const float* bo = (const float*)d_in[6];
  const float* Wc = (const float*)d_in[7];
  const float* bc = (const float*)d_in[8];
  float* out = (float*)d_out;

  int*   cnt  = (int*)d_ws;
  float* hbuf = (float*)((char*)d_ws + WS_HBUF);
  char*  diag = (ws_size >= (6u << 20)) ? ((char*)d_ws + WS_DIAG) : nullptr;

  hipMemsetAsync(d_ws, 0, WS_HBUF, stream);   // zero counters each call

  hipFuncSetAttribute((const void*)earliest_coop,
                      hipFuncAttributeMaxDynamicSharedMemorySize, SMEM_BYTES);

  void* args[] = { (void*)&X, (void*)&U, (void*)&Wk, (void*)&Wr, (void*)&bL,
                   (void*)&Wo, (void*)&bo, (void*)&Wc, (void*)&bc, (void*)&out,
                   (void*)&cnt, (void*)&hbuf, (void*)&diag };
  hipError_t lerr = hipLaunchCooperativeKernel((const void*)earliest_coop,
                                               dim3(NGRP * GWG), dim3(TPW),
                                               args, SMEM_BYTES, stream);
  if (lerr != hipSuccess) {
    hipLaunchKernelGGL(earliest_coop, dim3(NGRP * GWG), dim3(TPW), SMEM_BYTES, stream,
                       X, U, Wk, Wr, bL, Wo, bo, Wc, bc, out, cnt, hbuf, diag);
  }
}

// Round 12
// 167.590 us; speedup vs baseline: 1.1251x; 1.0823x over previous
//
#include <hip/hip_runtime.h>
#include <cstddef>
#include <cstdint>

#define NT_ 4096
#define NV_ 128
#define NH_ 256
#define NC_ 10
#define KT_ 384            // NV_ + NH_
#define NGRP 16            // sample groups
#define SB   8             // samples per group
#define GWG  16            // workgroups per group
#define TPW  256
#define VST  12            // v_lds row stride (floats), 16B-aligned, bank-clean
#define Z9   9             // zp row pad (float4s)
#define FULLMASK 255

// dynamic LDS partition (float offsets)
#define SM_W    0                        // 24576: weight slice (96KB)
#define SM_V    24576                    // 4608:  v = [x;h] rows [384][VST]
#define SM_ZP   (SM_V + KT_*VST)         // 29184: zp 64*Z9 float4 = 2304 (also leader head scratch)
#define SM_C    (SM_ZP + 2304)           // 31488: c[16][Z9]
#define SM_BL   (SM_C + 144)             // 31632: bias slice [64]
#define SM_WC   (SM_BL + 64)             // 31696: full Wc [257] (every WG)
#define SM_WO   (SM_WC + 260)            // 31956: leader Wo [256*10]
#define SM_HD   (SM_WO + 2560)           // 34516: bo[10], bc0
#define SM_RED  (SM_HD + 12)             // 34528: head wave partials [4][8]
#define SM_TOT  (SM_RED + 32)            // 34560 floats
#define SMEM_BYTES (SM_TOT * 4)          // 138240 B

// d_ws layout: cnt[16] @ stride 256B (4KB) ; hbuf[2][16][256][8] floats (128KB);
//              diag lines at +1MB (4MB, optional)
#define WS_HBUF  4096
#define WS_DIAG  (1u << 20)

#define ALD(p)    __hip_atomic_load((p), __ATOMIC_RELAXED, __HIP_MEMORY_SCOPE_AGENT)
#define AST(p,v)  __hip_atomic_store((p), (v), __ATOMIC_RELAXED, __HIP_MEMORY_SCOPE_AGENT)

#define FMA8(S) \
  acc[S].x = fmaf(w4.x, vs, acc[S].x); \
  acc[S].y = fmaf(w4.y, vs, acc[S].y); \
  acc[S].z = fmaf(w4.z, vs, acc[S].z); \
  acc[S].w = fmaf(w4.w, vs, acc[S].w);

#define ZSTEP(i)                                            \
  {                                                         \
    float4 w4 = wl4[(i) * 256 + wbase];                     \
    const float* vk = v_lds + ((i) * 16 + ks) * VST;        \
    float4 va = *(const float4*)(vk);                       \
    float4 vb = *(const float4*)(vk + 4);                   \
    { float vs = va.x; FMA8(0) } { float vs = va.y; FMA8(1) } \
    { float vs = va.z; FMA8(2) } { float vs = va.w; FMA8(3) } \
    { float vs = vb.x; FMA8(4) } { float vs = vb.y; FMA8(5) } \
    { float vs = vb.z; FMA8(6) } { float vs = vb.w; FMA8(7) } \
  }

extern "C" __global__ __launch_bounds__(TPW, 1)
void earliest_coop(const float* __restrict__ X, const float* __restrict__ U,
                   const float* __restrict__ Wk, const float* __restrict__ Wr,
                   const float* __restrict__ bl, const float* __restrict__ Wo,
                   const float* __restrict__ bo, const float* __restrict__ Wc,
                   const float* __restrict__ bc, float* __restrict__ out,
                   int* __restrict__ cnt, float* __restrict__ hbuf,
                   char* __restrict__ diag)
{
  extern __shared__ float smem[];
  float* w_lds = smem + SM_W;
  float* v_lds = smem + SM_V;
  float* zp    = smem + SM_ZP;
  float* c_lds = smem + SM_C;
  float* bl_s  = smem + SM_BL;
  float* wc_s  = smem + SM_WC;
  float* wo_s  = smem + SM_WO;
  float* hd_s  = smem + SM_HD;
  float* red   = smem + SM_RED;
  __shared__ int halted_lds;   // replicated (deterministic, identical in all WGs)
  __shared__ int wflags;       // samples needing an out-write this iter

  const int tid  = threadIdx.x;
  const int w    = blockIdx.x & 15;   // WG within group
  const int g    = blockIdx.x >> 4;   // group
  const int colq = tid & 15;          // col-quad within WG (16 x float4 = 64 cols)
  const int ks   = tid >> 4;          // K-split 0..15
  const bool leader = (w == 0);

  // ---- one-time: stage weight slice into LDS (swizzled) ----
  for (int m = 0; m < 24; ++m) {
    int idx4 = m * 256 + tid;
    int k = idx4 >> 4, cq = idx4 & 15;
    int rr = cq >> 2, qq = cq & 3;
    int col4 = rr * 64 + w * 4 + qq;            // float4 column index in [0,256)
    float4 wv;
    if (k < NV_) wv = ((const float4*)Wk)[(size_t)k * 256 + col4];
    else         wv = ((const float4*)Wr)[(size_t)(k - NV_) * 256 + col4];
    ((float4*)w_lds)[k * 16 + (cq ^ (k & 7))] = wv;
  }
  if (tid < 64) {
    int rr = tid >> 4, e = tid & 15;
    bl_s[tid] = bl[rr * 256 + w * 16 + e];
  }
  wc_s[tid] = Wc[tid];
  if (tid == 0) wc_s[256] = Wc[256];
  if (tid < 128) c_lds[(tid >> 3) * Z9 + (tid & 7)] = 0.f;
  if (leader) {
    for (int m = tid; m < NH_ * NC_; m += TPW) wo_s[m] = Wo[m];
  }
  if (tid < 10)  hd_s[tid] = bo[tid];
  if (tid == 10) hd_s[10] = bc[0];
  if (tid == 0)  { halted_lds = 0; wflags = 0; }

  int* cntg = cnt + (g << 6);
  const int cswz  = colq ^ (ks & 7);
  const int wbase = ks * 16 + cswz;
  const float4* wl4 = (const float4*)w_lds;

  // X staging decomposition: one float4 per thread per iter
  const int xk4 = tid >> 3;        // 0..31 (float4 row index)
  const int xs  = tid & 7;         // sample
  const float4* X4 = (const float4*)X;
  float4 xr = X4[((size_t)(g * SB + xs) * NT_ + 0) * 32 + xk4];  // prefetch it=0

  // h-load decomposition: 2 float4 per thread (f0 = tid, f1 = 256+tid)
  const int he0 = tid >> 1;                 // e for f0 (0..127)
  const int hs0 = (tid & 1) * 4;            // s0 for both

  __syncthreads();   // staging + shared-init visible; xr arrived
  // prologue: stage x(0), then Wk-pass for it=0
  {
    #pragma unroll
    for (int j = 0; j < 4; ++j)
      v_lds[(4 * xk4 + j) * VST + xs] = ((const float*)&xr)[j];
  }
  __syncthreads();   // x(0) visible for prologue Wk-pass

  float4 acc[8];     // persistent z accumulator (Wk part carried across sync)
  #pragma unroll
  for (int s = 0; s < 8; ++s) acc[s] = make_float4(0.f, 0.f, 0.f, 0.f);
  #pragma unroll
  for (int i = 0; i < 8; ++i) ZSTEP(i)   // x(0) @ Wk

  float uv_pf = 0.f;   // prefetched U(tau) for decision lanes

  for (int it = 0;; ++it) {
    // ---- A: stage h(it-1) into v_lds; reset wflags ----
    if (tid == 0) wflags = 0;
    if (it == 0) {
      #pragma unroll
      for (int i2 = 0; i2 < 8; ++i2) {
        int flat = i2 * 256 + tid;
        v_lds[(NV_ + (flat >> 3)) * VST + (flat & 7)] = 0.f;
      }
    } else {
      // vectorized sc1 h-load: 2 x dwordx4 per thread (same coherence path as
      // relaxed agent atomics, 4x fewer uncached transactions)
      const float4* hsrc4 = (const float4*)(hbuf + ((size_t)(it & 1) * NGRP + g) * NH_ * SB);
      const float4* p0 = hsrc4 + tid;
      const float4* p1 = p0 + 256;
      float4 a0, a1;
      asm volatile(
        "global_load_dwordx4 %0, %2, off sc1\n\t"
        "global_load_dwordx4 %1, %3, off sc1\n\t"
        "s_waitcnt vmcnt(0)"
        : "=&v"(a0), "=&v"(a1)
        : "v"(p0), "v"(p1)
        : "memory");
      *(float4*)(v_lds + (NV_ + he0) * VST + hs0)         = a0;
      *(float4*)(v_lds + (NV_ + 128 + he0) * VST + hs0)   = a1;
    }
    __syncthreads();   // B1: v_lds h region + wflags reset visible

    // ---- C: z h-part (i=8..23) + head partials + prefetches ----
    if (it < NT_) {
      if (it + 1 < NT_)   // prefetch X(it+1) (hidden under compute)
        xr = X4[((size_t)(g * SB + xs) * NT_ + (it + 1)) * 32 + xk4];
      #pragma unroll
      for (int i = 8; i < 24; ++i) ZSTEP(i)   // h(it-1) @ Wr (accumulates on Wk part)
      #pragma unroll
      for (int off = 16; off <= 32; off <<= 1) {
        #pragma unroll
        for (int s = 0; s < 8; ++s) {
          acc[s].x += __shfl_xor(acc[s].x, off, 64);
          acc[s].y += __shfl_xor(acc[s].y, off, 64);
          acc[s].z += __shfl_xor(acc[s].z, off, 64);
          acc[s].w += __shfl_xor(acc[s].w, off, 64);
        }
      }
      if ((tid & 48) == 0) {   // ks&3 == 0 lanes
        int w4 = tid >> 6;
        float4* zp4 = (float4*)zp;
        #pragma unroll
        for (int s = 0; s < 8; ++s) zp4[(w4 * 16 + colq) * Z9 + s] = acc[s];
      }
    }
    if (it >= 1) {
      // head partials for tau = it-1 (reads v_lds h region; independent of z)
      const float* hv = v_lds + (NV_ + tid) * VST;
      const float wcv = wc_s[tid];
      float part[SB];
      #pragma unroll
      for (int s = 0; s < SB; ++s) part[s] = hv[s] * wcv;
      #pragma unroll
      for (int off = 1; off <= 32; off <<= 1) {
        #pragma unroll
        for (int s = 0; s < SB; ++s) part[s] += __shfl_xor(part[s], off, 64);
      }
      if ((tid & 63) == 0) {
        int w4 = tid >> 6;
        #pragma unroll
        for (int s = 0; s < SB; ++s) red[w4 * 8 + s] = part[s];
      }
      if (tid >= 128 && tid < 128 + SB)
        uv_pf = U[(size_t)(g * SB + (tid - 128)) * NT_ + (it - 1)];
    }
    __syncthreads();   // B5: zp + red visible

    // ---- E: gates (waves 0-1) || halt decision (wave 2 lanes 0-7) ----
    if (it < NT_ && tid < 128) {
      int e = tid >> 3, s = tid & 7;
      float zg4[4];
      #pragma unroll
      for (int r = 0; r < 4; ++r) {
        int cq = r * 4 + (e >> 2);
        int j  = e & 3;
        float sum = 0.f;
        #pragma unroll
        for (int w4 = 0; w4 < 4; ++w4)
          sum += zp[((w4 * 16 + cq) * Z9 + s) * 4 + j];
        zg4[r] = sum + bl_s[r * 16 + e];
      }
      float gi = 1.f / (1.f + expf(-zg4[0]));
      float gf = 1.f / (1.f + expf(-zg4[1]));
      float gg = tanhf(zg4[2]);
      float go = 1.f / (1.f + expf(-zg4[3]));
      float c = gf * c_lds[e * Z9 + s] + gi * gg;
      c_lds[e * Z9 + s] = c;
      float h = go * tanhf(c);
      size_t hidx = (((size_t)((it + 1) & 1) * NGRP + g) * NH_ + (w * 16 + e)) * SB + s;
      AST(hbuf + hidx, h);
    }
    if (it >= 1 && tid >= 128 && tid < 128 + SB) {
      const int s_ = tid - 128;
      if (!((halted_lds >> s_) & 1)) {
        const int tau = it - 1;
        const float psum = red[0 * 8 + s_] + red[1 * 8 + s_] + red[2 * 8 + s_] + red[3 * 8 + s_];
        const float pre   = psum + (float)tau * wc_s[256] + hd_s[10];
        const float p     = 1.f / (1.f + expf(-pre));
        const float probs = 0.9f * p + 0.005f;
        const bool  a     = (uv_pf < probs);
        if (a || tau == NT_ - 1) atomicOr(&wflags, 1 << s_);
        if (a) atomicOr(&halted_lds, 1 << s_);
      }
    }
    __syncthreads();   // B6: h stores drained (vmcnt0) + halted/wflags visible

    // ---- H: sync-overlap window ----
    if (tid == 0) {   // arrival first (h already MALL-acked by B6)
      __hip_atomic_fetch_add(cntg, 1, __ATOMIC_RELAXED, __HIP_MEMORY_SCOPE_AGENT);
      if (diag)       // iteration meter: one 64B line per WG per iter (counted in WRITE_SIZE)
        __builtin_nontemporal_store(1u,
            (uint32_t*)(diag + (((size_t)blockIdx.x << 8) + (it & 255)) * 64));
    }

    if (it + 1 < NT_) { // stage x(it+1) (independent of the group sync)
      #pragma unroll
      for (int j = 0; j < 4; ++j)
        v_lds[(4 * xk4 + j) * VST + xs] = ((const float*)&xr)[j];
    }

    if (it >= 1 && leader && wflags) {   // rare: logits + softmax + out write
      const int e5 = tid >> 3, s = tid & 7;
      float accv[NC_];
      #pragma unroll
      for (int cc = 0; cc < NC_; ++cc) accv[cc] = 0.f;
      #pragma unroll
      for (int i2 = 0; i2 < 8; ++i2) {
        const int e = i2 * 32 + e5;
        const float hvv = v_lds[(NV_ + e) * VST + s];
        #pragma unroll
        for (int cc = 0; cc < NC_; ++cc) accv[cc] += hvv * wo_s[e * NC_ + cc];
      }
      #pragma unroll
      for (int off = 8; off <= 32; off <<= 1) {
        #pragma unroll
        for (int cc = 0; cc < NC_; ++cc) accv[cc] += __shfl_xor(accv[cc], off, 64);
      }
      if ((tid & 56) == 0) {
        const int w4 = tid >> 6;
        #pragma unroll
        for (int cc = 0; cc < NC_; ++cc) zp[(w4 * 8 + s) * NC_ + cc] = accv[cc];
      }
      __syncthreads();   // leader-local
      if (tid < SB && ((wflags >> tid) & 1)) {
        const int s_ = tid;
        float l[NC_];
        float mx = -1e30f;
        #pragma unroll
        for (int cc = 0; cc < NC_; ++cc) {
          l[cc] = zp[(0 * 8 + s_) * NC_ + cc] + zp[(1 * 8 + s_) * NC_ + cc]
                + zp[(2 * 8 + s_) * NC_ + cc] + zp[(3 * 8 + s_) * NC_ + cc] + hd_s[cc];
          mx = fmaxf(mx, l[cc]);
        }
        float ssum = 0.f;
        #pragma unroll
        for (int cc = 0; cc < NC_; ++cc) { l[cc] = expf(l[cc] - mx); ssum += l[cc]; }
        const float inv = 1.f / ssum;
        float* op = out + (g * SB + s_) * NC_;
        #pragma unroll
        for (int cc = 0; cc < NC_; ++cc) op[cc] = l[cc] * inv;
      }
      __syncthreads();   // leader-local: zp scratch free before next z-phase
    }

    if (halted_lds == FULLMASK || it == NT_) break;   // identical decision in all WGs

    __syncthreads();   // B6b: x(it+1) visible for the Wk-pass

    // ---- W: Wk-pass for z(it+1) — fills the sync window with local work ----
    #pragma unroll
    for (int s = 0; s < 8; ++s) acc[s] = make_float4(0.f, 0.f, 0.f, 0.f);
    if (it + 1 < NT_) {
      #pragma unroll
      for (int i = 0; i < 8; ++i) ZSTEP(i)   // x(it+1) @ Wk
    }

    // ---- spin (mostly pre-satisfied after the Wk-pass) ----
    if (tid == 0) {
      const int target = GWG * (it + 1);
      while (ALD(cntg) < target) __builtin_amdgcn_s_sleep(1);
    }
    __syncthreads();   // B7
  }
}

extern "C" void kernel_launch(void* const* d_in, const int* in_sizes, int n_in,
                              void* d_out, int out_size, void* d_ws, size_t ws_size,
                              hipStream_t stream)
{
  const float* X  = (const float*)d_in[0];
  const float* U  = (const float*)d_in[1];
  const float* Wk = (const float*)d_in[2];
  const float* Wr = (const float*)d_in[3];
  const float* bL = (const float*)d_in[4];
  const float* Wo = (const float*)d_in[5];
  const float* bo = (const float*)d_in[6];
  const float* Wc = (const float*)d_in[7];
  const float* bc = (const float*)d_in[8];
  float* out = (float*)d_out;

  int*   cnt  = (int*)d_ws;
  float* hbuf = (float*)((char*)d_ws + WS_HBUF);
  char*  diag = (ws_size >= (6u << 20)) ? ((char*)d_ws + WS_DIAG) : nullptr;

  hipMemsetAsync(d_ws, 0, WS_HBUF, stream);   // zero counters each call

  hipFuncSetAttribute((const void*)earliest_coop,
                      hipFuncAttributeMaxDynamicSharedMemorySize, SMEM_BYTES);

  void* args[] = { (void*)&X, (void*)&U, (void*)&Wk, (void*)&Wr, (void*)&bL,
                   (void*)&Wo, (void*)&bo, (void*)&Wc, (void*)&bc, (void*)&out,
                   (void*)&cnt, (void*)&hbuf, (void*)&diag };
  hipError_t lerr = hipLaunchCooperativeKernel((const void*)earliest_coop,
                                               dim3(NGRP * GWG), dim3(TPW),
                                               args, SMEM_BYTES, stream);
  if (lerr != hipSuccess) {
    hipLaunchKernelGGL(earliest_coop, dim3(NGRP * GWG), dim3(TPW), SMEM_BYTES, stream,
                       X, U, Wk, Wr, bL, Wo, bo, Wc, bc, out, cnt, hbuf, diag);
  }
}